// Round 1
// baseline (209.576 us; speedup 1.0000x reference)
//
#include <hip/hip_runtime.h>

// L2 normalize over last dim: feats [64, 4096, 512] fp32.
// 262,144 rows x 512 floats. One wave (64 lanes) per row:
//   - 2x float4 coalesced loads per lane (16B/lane, 1KB/wave-instruction)
//   - per-lane sum of squares, 6-step shfl_xor butterfly reduce over 64 lanes
//   - rsqrtf + scale + 2x float4 stores
// Memory-bound: ~1.07 GB traffic -> ~170us floor at 6.3 TB/s.

__global__ __launch_bounds__(256) void l2norm_rows_kernel(
    const float* __restrict__ in, float* __restrict__ out, int nrows) {
  const int lane = threadIdx.x & 63;
  const int wave_in_block = threadIdx.x >> 6;
  const int waves_per_block = blockDim.x >> 6;  // 4
  int wave = blockIdx.x * waves_per_block + wave_in_block;
  const int total_waves = gridDim.x * waves_per_block;

  for (int row = wave; row < nrows; row += total_waves) {
    const float4* rp = reinterpret_cast<const float4*>(in + (size_t)row * 512);
    float4 a = rp[lane];        // floats [lane*4 .. lane*4+3]
    float4 b = rp[lane + 64];   // floats [256 + lane*4 ..]

    float s = a.x * a.x + a.y * a.y + a.z * a.z + a.w * a.w +
              b.x * b.x + b.y * b.y + b.z * b.z + b.w * b.w;

    // 64-lane butterfly reduction (wave = 64 on CDNA, not 32)
    #pragma unroll
    for (int off = 32; off > 0; off >>= 1) s += __shfl_xor(s, off, 64);

    const float scale = rsqrtf(s);

    a.x *= scale; a.y *= scale; a.z *= scale; a.w *= scale;
    b.x *= scale; b.y *= scale; b.z *= scale; b.w *= scale;

    float4* op = reinterpret_cast<float4*>(out + (size_t)row * 512);
    op[lane] = a;
    op[lane + 64] = b;
  }
}

extern "C" void kernel_launch(void* const* d_in, const int* in_sizes, int n_in,
                              void* d_out, int out_size, void* d_ws, size_t ws_size,
                              hipStream_t stream) {
  const float* feats = (const float*)d_in[0];
  float* out = (float*)d_out;
  const int nrows = in_sizes[0] / 512;  // 262,144

  // 2048 blocks x 256 threads = 8192 waves; 32 rows per wave (grid-stride).
  // 8 blocks/CU -> 32 waves/CU occupancy for latency hiding.
  const int block = 256;
  int grid = 2048;
  const int waves_needed = (nrows + 0) / (block / 64);
  if (grid > waves_needed) grid = waves_needed > 0 ? waves_needed : 1;

  l2norm_rows_kernel<<<grid, block, 0, stream>>>(feats, out, nrows);
}

// Round 3
// 190.705 us; speedup vs baseline: 1.0990x; 1.0990x over previous
//
#include <hip/hip_runtime.h>

// L2 normalize over last dim: feats [64, 4096, 512] fp32.
// 262,144 rows x 512 floats. One wave (64 lanes) per row, 2 rows per
// iteration for memory-level parallelism:
//   - 4x 16B nontemporal coalesced loads in flight per wave iteration
//   - two interleaved 6-step shfl_xor butterfly reduces (ILP)
//   - rsqrtf + scale + nontemporal 16B stores
// Memory-bound: ~1.07 GB traffic -> ~170us floor at 6.3 TB/s copy ceiling.
//
// NOTE: __builtin_nontemporal_* requires a NATIVE vector type, not HIP's
// float4 class -> use ext_vector_type(4).

typedef float f32x4 __attribute__((ext_vector_type(4)));

__device__ __forceinline__ float sumsq8(f32x4 a, f32x4 b) {
  return a.x * a.x + a.y * a.y + a.z * a.z + a.w * a.w +
         b.x * b.x + b.y * b.y + b.z * b.z + b.w * b.w;
}

__global__ __launch_bounds__(256) void l2norm_rows_kernel(
    const float* __restrict__ in, float* __restrict__ out, int nrows) {
  const int lane = threadIdx.x & 63;
  const int wave_in_block = threadIdx.x >> 6;
  const int waves_per_block = blockDim.x >> 6;  // 4
  const int wave = blockIdx.x * waves_per_block + wave_in_block;
  const int total_waves = gridDim.x * waves_per_block;

  // Main loop: 2 rows per iteration. Consecutive waves sweep consecutive
  // row pairs -> fully contiguous access across the grid.
  int row = wave * 2;
  const int stride = total_waves * 2;
  for (; row + 1 < nrows; row += stride) {
    const f32x4* rp0 = reinterpret_cast<const f32x4*>(in + (size_t)row * 512);
    const f32x4* rp1 = reinterpret_cast<const f32x4*>(in + (size_t)(row + 1) * 512);

    // 4 independent loads in flight (nontemporal: touch-once stream)
    f32x4 a0 = __builtin_nontemporal_load(rp0 + lane);
    f32x4 b0 = __builtin_nontemporal_load(rp0 + lane + 64);
    f32x4 a1 = __builtin_nontemporal_load(rp1 + lane);
    f32x4 b1 = __builtin_nontemporal_load(rp1 + lane + 64);

    float s0 = sumsq8(a0, b0);
    float s1 = sumsq8(a1, b1);

    // Two interleaved 64-lane butterfly reductions (independent chains)
    #pragma unroll
    for (int off = 32; off > 0; off >>= 1) {
      s0 += __shfl_xor(s0, off, 64);
      s1 += __shfl_xor(s1, off, 64);
    }

    const float sc0 = rsqrtf(s0);
    const float sc1 = rsqrtf(s1);

    a0 *= sc0;
    b0 *= sc0;
    a1 *= sc1;
    b1 *= sc1;

    f32x4* op0 = reinterpret_cast<f32x4*>(out + (size_t)row * 512);
    f32x4* op1 = reinterpret_cast<f32x4*>(out + (size_t)(row + 1) * 512);
    __builtin_nontemporal_store(a0, op0 + lane);
    __builtin_nontemporal_store(b0, op0 + lane + 64);
    __builtin_nontemporal_store(a1, op1 + lane);
    __builtin_nontemporal_store(b1, op1 + lane + 64);
  }

  // Tail: at most one leftover row per wave (exactly zero for this shape).
  if (row < nrows) {
    const f32x4* rp = reinterpret_cast<const f32x4*>(in + (size_t)row * 512);
    f32x4 a = __builtin_nontemporal_load(rp + lane);
    f32x4 b = __builtin_nontemporal_load(rp + lane + 64);
    float s = sumsq8(a, b);
    #pragma unroll
    for (int off = 32; off > 0; off >>= 1) s += __shfl_xor(s, off, 64);
    const float sc = rsqrtf(s);
    a *= sc;
    b *= sc;
    f32x4* op = reinterpret_cast<f32x4*>(out + (size_t)row * 512);
    __builtin_nontemporal_store(a, op + lane);
    __builtin_nontemporal_store(b, op + lane + 64);
  }
}

extern "C" void kernel_launch(void* const* d_in, const int* in_sizes, int n_in,
                              void* d_out, int out_size, void* d_ws, size_t ws_size,
                              hipStream_t stream) {
  const float* feats = (const float*)d_in[0];
  float* out = (float*)d_out;
  const int nrows = in_sizes[0] / 512;  // 262,144

  // 2048 blocks x 256 threads = 8192 waves; 16 iterations x 2 rows per wave.
  // 8 blocks/CU -> 32 waves/CU occupancy for latency hiding.
  const int block = 256;
  int grid = 2048;
  const int pairs = nrows / (2 * (block / 64));
  if (grid > pairs && pairs > 0) grid = pairs;

  l2norm_rows_kernel<<<grid, block, 0, stream>>>(feats, out, nrows);
}

// Round 4
// 190.450 us; speedup vs baseline: 1.1004x; 1.0013x over previous
//
#include <hip/hip_runtime.h>

// L2 normalize over last dim: feats [64, 4096, 512] fp32.
// 262,144 rows x 512 floats. One wave (64 lanes) per row, 4 rows per
// iteration for memory-level parallelism:
//   - 8x 16B nontemporal coalesced loads in flight per wave iteration
//   - four interleaved 6-step shfl_xor butterfly reduces (ILP over the
//     ~200cy cross-lane reduce chain)
//   - rsqrtf + scale + nontemporal 16B stores
// Memory-bound: ~1.07 GB traffic -> ~170us floor at 6.3 TB/s copy ceiling.
// R3 measured 190.7us (5.63 TB/s); this round doubles loads-in-flight.

typedef float f32x4 __attribute__((ext_vector_type(4)));

__device__ __forceinline__ float sumsq8(f32x4 a, f32x4 b) {
  return a.x * a.x + a.y * a.y + a.z * a.z + a.w * a.w +
         b.x * b.x + b.y * b.y + b.z * b.z + b.w * b.w;
}

__global__ __launch_bounds__(256) void l2norm_rows_kernel(
    const float* __restrict__ in, float* __restrict__ out, int nrows) {
  const int lane = threadIdx.x & 63;
  const int wave_in_block = threadIdx.x >> 6;
  const int waves_per_block = blockDim.x >> 6;  // 4
  const int wave = blockIdx.x * waves_per_block + wave_in_block;
  const int total_waves = gridDim.x * waves_per_block;

  // Main loop: 4 rows per iteration. Consecutive waves sweep consecutive
  // row quads -> fully contiguous access across the grid.
  int row = wave * 4;
  const int stride = total_waves * 4;
  for (; row + 3 < nrows; row += stride) {
    const f32x4* rp0 = reinterpret_cast<const f32x4*>(in + (size_t)row * 512);
    const f32x4* rp1 = rp0 + 128;
    const f32x4* rp2 = rp0 + 256;
    const f32x4* rp3 = rp0 + 384;

    // 8 independent loads in flight (nontemporal: touch-once stream)
    f32x4 a0 = __builtin_nontemporal_load(rp0 + lane);
    f32x4 b0 = __builtin_nontemporal_load(rp0 + lane + 64);
    f32x4 a1 = __builtin_nontemporal_load(rp1 + lane);
    f32x4 b1 = __builtin_nontemporal_load(rp1 + lane + 64);
    f32x4 a2 = __builtin_nontemporal_load(rp2 + lane);
    f32x4 b2 = __builtin_nontemporal_load(rp2 + lane + 64);
    f32x4 a3 = __builtin_nontemporal_load(rp3 + lane);
    f32x4 b3 = __builtin_nontemporal_load(rp3 + lane + 64);

    float s0 = sumsq8(a0, b0);
    float s1 = sumsq8(a1, b1);
    float s2 = sumsq8(a2, b2);
    float s3 = sumsq8(a3, b3);

    // Four interleaved 64-lane butterfly reductions (independent chains)
    #pragma unroll
    for (int off = 32; off > 0; off >>= 1) {
      s0 += __shfl_xor(s0, off, 64);
      s1 += __shfl_xor(s1, off, 64);
      s2 += __shfl_xor(s2, off, 64);
      s3 += __shfl_xor(s3, off, 64);
    }

    const float sc0 = rsqrtf(s0);
    const float sc1 = rsqrtf(s1);
    const float sc2 = rsqrtf(s2);
    const float sc3 = rsqrtf(s3);

    a0 *= sc0; b0 *= sc0;
    a1 *= sc1; b1 *= sc1;
    a2 *= sc2; b2 *= sc2;
    a3 *= sc3; b3 *= sc3;

    f32x4* op0 = reinterpret_cast<f32x4*>(out + (size_t)row * 512);
    f32x4* op1 = op0 + 128;
    f32x4* op2 = op0 + 256;
    f32x4* op3 = op0 + 384;
    __builtin_nontemporal_store(a0, op0 + lane);
    __builtin_nontemporal_store(b0, op0 + lane + 64);
    __builtin_nontemporal_store(a1, op1 + lane);
    __builtin_nontemporal_store(b1, op1 + lane + 64);
    __builtin_nontemporal_store(a2, op2 + lane);
    __builtin_nontemporal_store(b2, op2 + lane + 64);
    __builtin_nontemporal_store(a3, op3 + lane);
    __builtin_nontemporal_store(b3, op3 + lane + 64);
  }

  // Tail: up to 3 leftover rows per wave (exactly zero for this shape).
  for (; row < nrows; ++row) {
    const f32x4* rp = reinterpret_cast<const f32x4*>(in + (size_t)row * 512);
    f32x4 a = __builtin_nontemporal_load(rp + lane);
    f32x4 b = __builtin_nontemporal_load(rp + lane + 64);
    float s = sumsq8(a, b);
    #pragma unroll
    for (int off = 32; off > 0; off >>= 1) s += __shfl_xor(s, off, 64);
    const float sc = rsqrtf(s);
    a *= sc;
    b *= sc;
    f32x4* op = reinterpret_cast<f32x4*>(out + (size_t)row * 512);
    __builtin_nontemporal_store(a, op + lane);
    __builtin_nontemporal_store(b, op + lane + 64);
  }
}

extern "C" void kernel_launch(void* const* d_in, const int* in_sizes, int n_in,
                              void* d_out, int out_size, void* d_ws, size_t ws_size,
                              hipStream_t stream) {
  const float* feats = (const float*)d_in[0];
  float* out = (float*)d_out;
  const int nrows = in_sizes[0] / 512;  // 262,144

  // 2048 blocks x 256 threads = 8192 waves; 8 iterations x 4 rows per wave.
  // 8 blocks/CU -> 32 waves/CU occupancy for latency hiding.
  const int block = 256;
  int grid = 2048;
  const int quads = nrows / (4 * (block / 64));
  if (grid > quads && quads > 0) grid = quads;

  l2norm_rows_kernel<<<grid, block, 0, stream>>>(feats, out, nrows);
}